// Round 2
// 2286.829 us; speedup vs baseline: 1.1368x; 1.1368x over previous
//
#include <hip/hip_runtime.h>

typedef unsigned short ushort_t;
typedef __bf16 bf16x8 __attribute__((ext_vector_type(8)));
typedef float f32x4 __attribute__((ext_vector_type(4)));

// ---- problem constants ----
constexpr int V_  = 32000;
constexpr int DM_ = 1024;
constexpr int DS_ = 16;
constexpr int DI_ = 2048;
constexpr int DTR_= 64;
constexpr int B_  = 2;
constexpr int L_  = 2048;
constexpr int M_  = B_ * L_;     // 4096 rows
constexpr int NXZ_= 2 * DI_;     // 4096

// ---- workspace layout (bytes, all 256-aligned) ----
constexpr size_t OFF_W_IN   = 0;                                  // 4096x1024 bf16 = 8 MB
constexpr size_t OFF_W_OUT  = OFF_W_IN   + (size_t)NXZ_*DM_*2;    // 1024x2048 bf16 = 4 MB
constexpr size_t OFF_W_HEAD = OFF_W_OUT  + (size_t)DM_*DI_*2;     // 32000x1024 bf16 = 62.5 MB
constexpr size_t OFF_EMB    = OFF_W_HEAD + (size_t)V_*DM_*2;      // 4096x1024 bf16
constexpr size_t OFF_XZ     = OFF_EMB    + (size_t)M_*DM_*2;      // 4096x4096 f32 = 64 MB
constexpr size_t OFF_X      = OFF_XZ     + (size_t)M_*NXZ_*4;     // 4096x2048 f32 = 32 MB
constexpr size_t OFF_DBC    = OFF_X      + (size_t)M_*DI_*4;      // 4096x96 f32
constexpr size_t OFF_DT     = OFF_DBC    + (size_t)M_*96*4;       // 4096x2048 f32 = 32 MB
constexpr size_t OFF_Y      = OFF_DT     + (size_t)M_*DI_*4;      // 4096x2048 bf16 = 16 MB
constexpr size_t OFF_MO     = OFF_Y      + (size_t)M_*DI_*2;      // 4096x1024 bf16 = 8 MB

__device__ __forceinline__ ushort_t f2bf(float f) {
  union { float f; unsigned u; } v; v.f = f;
  unsigned r = v.u + 0x7FFFu + ((v.u >> 16) & 1u);
  return (ushort_t)(r >> 16);
}

__device__ __forceinline__ void async16(const void* g, void* l) {
  __builtin_amdgcn_global_load_lds(
      (const __attribute__((address_space(1))) unsigned int*)g,
      (__attribute__((address_space(3))) unsigned int*)l, 16, 0, 0);
}

// ---- f32 -> bf16 converter (RNE), 4 elems/thread ----
__global__ __launch_bounds__(256) void cvt_bf16_kernel(
    const float* __restrict__ in, ushort_t* __restrict__ out, int n4) {
  int i = blockIdx.x * 256 + threadIdx.x;
  if (i >= n4) return;
  float4 v = ((const float4*)in)[i];
  ushort4 o;
  o.x = f2bf(v.x); o.y = f2bf(v.y); o.z = f2bf(v.z); o.w = f2bf(v.w);
  ((ushort4*)out)[i] = o;
}

// ---- embedding gather -> bf16, 4 elems/thread ----
__global__ __launch_bounds__(256) void gather_kernel(
    const int* __restrict__ tokens, const float* __restrict__ embed,
    ushort_t* __restrict__ out) {
  int i = blockIdx.x * 256 + threadIdx.x;    // over M_*DM_/4
  int row = i >> 8;                          // DM_/4 = 256 vec4 per row
  int c4 = i & 255;
  int tok = tokens[row];
  float4 v = ((const float4*)(embed + (size_t)tok * DM_))[c4];
  ushort4 o;
  o.x = f2bf(v.x); o.y = f2bf(v.y); o.z = f2bf(v.z); o.w = f2bf(v.w);
  ((ushort4*)out)[(size_t)row * 256 + c4] = o;
}

// ---- bf16 MFMA GEMM: C[M x N] = A[M x K] * B[N x K]^T ----
// EPI 0: f32 store; 1: bf16 store; 2: f32 + bias store
template <int EPI>
__global__ __launch_bounds__(256) void gemm_bt_kernel(
    const ushort_t* __restrict__ A, const ushort_t* __restrict__ Bw,
    float* __restrict__ Cf, ushort_t* __restrict__ Cb,
    const float* __restrict__ bias, int Ncols, int K) {
  // LDS tiles in fragment order: [kquad 0..3][row 0..127][8 bf16] (16B per row-quad)
  __shared__ __attribute__((aligned(16))) ushort_t lds_a[4 * 128 * 8];
  __shared__ __attribute__((aligned(16))) ushort_t lds_b[4 * 128 * 8];
  const int tid  = threadIdx.x;
  const int lane = tid & 63;
  const int wave = tid >> 6;
  const int wm = wave & 1;
  const int wn = wave >> 1;
  const int row0 = blockIdx.y * 128;
  const int col0 = blockIdx.x * 128;

  f32x4 acc[4][4];
#pragma unroll
  for (int i = 0; i < 4; ++i)
#pragma unroll
    for (int j = 0; j < 4; ++j) acc[i][j] = f32x4{0.f, 0.f, 0.f, 0.f};

  // staging: 8 slices of 1024B per tile; wave w stages slices {2w, 2w+1} of A and B.
  // slice s, lane -> linear i = s*64+lane; q = i>>7, row = i&127;
  // lane loads global [row0+row][k0 + q*8 .. +8) (16B); LDS dest = base + lane*16.
  const int sA0 = 2 * wave, sA1 = 2 * wave + 1;
  const int iA0 = sA0 * 64 + lane, iA1 = sA1 * 64 + lane;
  const ushort_t* pa0 = A  + (size_t)(row0 + (iA0 & 127)) * K + (iA0 >> 7) * 8;
  const ushort_t* pa1 = A  + (size_t)(row0 + (iA1 & 127)) * K + (iA1 >> 7) * 8;
  const ushort_t* pb0 = Bw + (size_t)(col0 + (iA0 & 127)) * K + (iA0 >> 7) * 8;
  const ushort_t* pb1 = Bw + (size_t)(col0 + (iA1 & 127)) * K + (iA1 >> 7) * 8;
  ushort_t* la0 = lds_a + sA0 * 512;
  ushort_t* la1 = lds_a + sA1 * 512;
  ushort_t* lb0 = lds_b + sA0 * 512;
  ushort_t* lb1 = lds_b + sA1 * 512;

  const int q = lane >> 4;
  const int r = lane & 15;

  for (int k0 = 0; k0 < K; k0 += 32) {
    async16(pa0 + k0, la0);
    async16(pa1 + k0, la1);
    async16(pb0 + k0, lb0);
    async16(pb1 + k0, lb1);
    __syncthreads();  // drains vmcnt -> LDS tile ready
    bf16x8 af[4], bfr[4];
#pragma unroll
    for (int i = 0; i < 4; ++i) {
      af[i]  = *(const bf16x8*)(lds_a + ((size_t)q * 128 + wm * 64 + i * 16 + r) * 8);
      bfr[i] = *(const bf16x8*)(lds_b + ((size_t)q * 128 + wn * 64 + i * 16 + r) * 8);
    }
#pragma unroll
    for (int i = 0; i < 4; ++i)
#pragma unroll
      for (int j = 0; j < 4; ++j)
        acc[i][j] = __builtin_amdgcn_mfma_f32_16x16x32_bf16(af[i], bfr[j], acc[i][j], 0, 0, 0);
    __syncthreads();  // all reads done before next stage overwrites
  }

#pragma unroll
  for (int i = 0; i < 4; ++i) {
#pragma unroll
    for (int j = 0; j < 4; ++j) {
      const int col = col0 + wn * 64 + j * 16 + r;
#pragma unroll
      for (int t = 0; t < 4; ++t) {
        const int row = row0 + wm * 64 + i * 16 + q * 4 + t;
        const float v = acc[i][j][t];
        if (EPI == 0) {
          Cf[(size_t)row * Ncols + col] = v;
        } else if (EPI == 1) {
          Cb[(size_t)row * Ncols + col] = f2bf(v);
        } else {
          Cf[(size_t)row * Ncols + col] = v + bias[col];
        }
      }
    }
  }
}

// ---- causal depthwise conv (DC=4) + bias + SiLU ----
__global__ __launch_bounds__(256) void conv_silu_kernel(
    const float* __restrict__ xz, const float* __restrict__ conv_w,
    const float* __restrict__ conv_b, float* __restrict__ x_f32) {
  int i = blockIdx.x * 256 + threadIdx.x;  // over M_*DI_
  int d = i & (DI_ - 1);
  int l = (i >> 11) & (L_ - 1);
  int b = i >> 22;
  const float4 w = ((const float4*)conv_w)[d];
  size_t rb = ((size_t)(b * L_ + l)) * NXZ_ + d;  // x part of xz
  float acc = conv_b[d] + w.w * xz[rb];
  if (l >= 1) acc += w.z * xz[rb - NXZ_];
  if (l >= 2) acc += w.y * xz[rb - 2 * (size_t)NXZ_];
  if (l >= 3) acc += w.x * xz[rb - 3 * (size_t)NXZ_];
  float s = acc / (1.f + __expf(-acc));  // silu
  x_f32[i] = s;
}

// ---- x_proj: dbc[row][0..96) = x_row(2048) . x_proj_w[e](2048), f32 ----
__global__ __launch_bounds__(256) void xproj_kernel(
    const float* __restrict__ x, const float* __restrict__ w,
    float* __restrict__ dbc) {
  __shared__ __attribute__((aligned(16))) float sx[DI_];
  int row = blockIdx.x;
  const float4* xr = (const float4*)(x + (size_t)row * DI_);
  for (int j = threadIdx.x; j < DI_ / 4; j += 256) ((float4*)sx)[j] = xr[j];
  __syncthreads();
  if (threadIdx.x < 96) {
    const float4* wr = (const float4*)(w + (size_t)threadIdx.x * DI_);
    float acc = 0.f;
    for (int k = 0; k < DI_ / 4; ++k) {
      float4 a = ((const float4*)sx)[k];
      float4 bb = wr[k];
      acc += a.x * bb.x + a.y * bb.y + a.z * bb.z + a.w * bb.w;
    }
    dbc[(size_t)row * 96 + threadIdx.x] = acc;
  }
}

// ---- dt_proj + softplus: dt[row][d] = softplus(dtraw_row(64) . w[d](64) + b[d]) ----
__global__ __launch_bounds__(256) void dtproj_kernel(
    const float* __restrict__ dbc, const float* __restrict__ w,
    const float* __restrict__ bias, float* __restrict__ dt_full) {
  __shared__ __attribute__((aligned(16))) float sdt[DTR_];
  int row = blockIdx.x;
  if (threadIdx.x < 16)
    ((float4*)sdt)[threadIdx.x] = ((const float4*)(dbc + (size_t)row * 96))[threadIdx.x];
  __syncthreads();
#pragma unroll
  for (int jj = 0; jj < 8; ++jj) {
    int d = threadIdx.x + jj * 256;
    const float4* wr = (const float4*)(w + (size_t)d * DTR_);
    float acc = bias[d];
#pragma unroll
    for (int k = 0; k < DTR_ / 4; ++k) {
      float4 a = ((const float4*)sdt)[k];
      float4 bb = wr[k];
      acc += a.x * bb.x + a.y * bb.y + a.z * bb.z + a.w * bb.w;
    }
    float sp = (acc > 15.f) ? acc : log1pf(__expf(acc));
    dt_full[(size_t)row * DI_ + d] = sp;
  }
}

// ---- selective scan v2: thread per (b,d,s); latency-pipelined ----
// (resubmission -- round 1 bench was an infra failure, kernel never ran)
//  * 16-step sub-chunks: dA/dB precomputed (no exp/LDS on the h-chain),
//    h-chain is 16 bare FMAs, p-reductions batched per shuffle stage
//    (16-way ILP) instead of a serial 4-deep shuffle chain per step.
//  * LDS double-buffer + T14 async-stage split: next chunk's global loads
//    issued into registers BEFORE compute, ds_write after -> HBM latency
//    hides under compute; one barrier per 64-step chunk.
__global__ __launch_bounds__(256) void scan_kernel(
    const float* __restrict__ dt_full, const float* __restrict__ x_f32,
    const float* __restrict__ xz, const float* __restrict__ dbc,
    const float* __restrict__ A_log, const float* __restrict__ Dvec,
    ushort_t* __restrict__ y_bf) {
  const int b  = blockIdx.x >> 7;            // 128 blocks per batch
  const int d0 = (blockIdx.x & 127) << 4;    // 16 channels per block
  const int tid = threadIdx.x;
  const int ch = tid >> 4;                   // 0..15 local channel
  const int s  = tid & 15;                   // state index
  const int d  = d0 + ch;
  const float a  = -__expf(A_log[(size_t)d * DS_ + s]);
  const float Dd = Dvec[d];
  float h = 0.f;
  __shared__ float s_dt[2][64][16], s_u[2][64][16], s_z[2][64][16],
                   s_B[2][64][16], s_C[2][64][16];
  const size_t rowbase = (size_t)b * L_;

  // staging decomposition: element i = tid + rr*256 -> ll = i>>4 (timestep), j = i&15
  int ll_[4], j_[4];
#pragma unroll
  for (int rr = 0; rr < 4; ++rr) {
    int i = tid + rr * 256;
    ll_[rr] = i >> 4;
    j_[rr] = i & 15;
  }

  // prologue: stage chunk 0 into buffer 0
#pragma unroll
  for (int rr = 0; rr < 4; ++rr) {
    const size_t row = rowbase + ll_[rr];
    s_dt[0][ll_[rr]][j_[rr]] = dt_full[row * DI_ + d0 + j_[rr]];
    s_u [0][ll_[rr]][j_[rr]] = x_f32 [row * DI_ + d0 + j_[rr]];
    s_z [0][ll_[rr]][j_[rr]] = xz    [row * NXZ_ + DI_ + d0 + j_[rr]];
    s_B [0][ll_[rr]][j_[rr]] = dbc   [row * 96 + DTR_ + j_[rr]];
    s_C [0][ll_[rr]][j_[rr]] = dbc   [row * 96 + DTR_ + DS_ + j_[rr]];
  }
  __syncthreads();

  for (int chunk = 0; chunk < L_ / 64; ++chunk) {
    const int cur = chunk & 1;
    const bool more = (chunk + 1 < L_ / 64);
    // T14 issue-early: next chunk's global loads into registers (latency
    // hides under this chunk's compute; ds_write happens after compute).
    float rdt[4], ru[4], rz[4], rB[4], rC[4];
    if (more) {
      const int l1 = (chunk + 1) * 64;
#pragma unroll
      for (int rr = 0; rr < 4; ++rr) {
        const size_t row = rowbase + l1 + ll_[rr];
        rdt[rr] = dt_full[row * DI_ + d0 + j_[rr]];
        ru [rr] = x_f32 [row * DI_ + d0 + j_[rr]];
        rz [rr] = xz    [row * NXZ_ + DI_ + d0 + j_[rr]];
        rB [rr] = dbc   [row * 96 + DTR_ + j_[rr]];
        rC [rr] = dbc   [row * 96 + DTR_ + DS_ + j_[rr]];
      }
    }
#pragma unroll 1
    for (int t0 = 0; t0 < 64; t0 += 16) {
      float dA[16], dB[16], p[16];
      // phase 1: independent per-step precompute (off the h critical path)
#pragma unroll
      for (int t = 0; t < 16; ++t) {
        const float dtv = s_dt[cur][t0 + t][ch];
        const float uv  = s_u [cur][t0 + t][ch];
        dA[t] = __expf(dtv * a);
        dB[t] = dtv * uv * s_B[cur][t0 + t][s];
      }
      // phase 2: the only true serial chain -- 16 bare FMAs
#pragma unroll
      for (int t = 0; t < 16; ++t) {
        h = dA[t] * h + dB[t];
        p[t] = h * s_C[cur][t0 + t][s];
      }
      // phase 3: batched shuffle reductions (16-way ILP per stage)
#pragma unroll
      for (int t = 0; t < 16; ++t) p[t] += __shfl_xor(p[t], 8, 16);
#pragma unroll
      for (int t = 0; t < 16; ++t) p[t] += __shfl_xor(p[t], 4, 16);
#pragma unroll
      for (int t = 0; t < 16; ++t) p[t] += __shfl_xor(p[t], 2, 16);
#pragma unroll
      for (int t = 0; t < 16; ++t) p[t] += __shfl_xor(p[t], 1, 16);
      // phase 4: epilogue + store (one lane per channel)
      if (s == 0) {
#pragma unroll
        for (int t = 0; t < 16; ++t) {
          const float uv = s_u[cur][t0 + t][ch];
          float y = p[t] + uv * Dd;
          const float zv = s_z[cur][t0 + t][ch];
          y *= zv / (1.f + __expf(-zv));
          y_bf[(rowbase + chunk * 64 + t0 + t) * DI_ + d] = f2bf(y);
        }
      }
    }
    // T14 write-late: commit next chunk into the other buffer
    if (more) {
      const int nb = cur ^ 1;
#pragma unroll
      for (int rr = 0; rr < 4; ++rr) {
        s_dt[nb][ll_[rr]][j_[rr]] = rdt[rr];
        s_u [nb][ll_[rr]][j_[rr]] = ru [rr];
        s_z [nb][ll_[rr]][j_[rr]] = rz [rr];
        s_B [nb][ll_[rr]][j_[rr]] = rB [rr];
        s_C [nb][ll_[rr]][j_[rr]] = rC [rr];
      }
    }
    __syncthreads();
  }
}

extern "C" void kernel_launch(void* const* d_in, const int* in_sizes, int n_in,
                              void* d_out, int out_size, void* d_ws, size_t ws_size,
                              hipStream_t stream) {
  const int*   tokens     = (const int*)d_in[0];
  const float* embed      = (const float*)d_in[1];
  const float* in_proj_w  = (const float*)d_in[2];
  const float* conv_w     = (const float*)d_in[3];
  const float* conv_b     = (const float*)d_in[4];
  const float* x_proj_w   = (const float*)d_in[5];
  const float* dt_proj_w  = (const float*)d_in[6];
  const float* dt_proj_b  = (const float*)d_in[7];
  const float* A_log      = (const float*)d_in[8];
  const float* Dvec       = (const float*)d_in[9];
  const float* out_proj_w = (const float*)d_in[10];
  const float* head_w     = (const float*)d_in[11];
  const float* head_b     = (const float*)d_in[12];
  float* out = (float*)d_out;

  char* ws = (char*)d_ws;
  ushort_t* w_in_bf   = (ushort_t*)(ws + OFF_W_IN);
  ushort_t* w_out_bf  = (ushort_t*)(ws + OFF_W_OUT);
  ushort_t* w_head_bf = (ushort_t*)(ws + OFF_W_HEAD);
  ushort_t* emb_bf    = (ushort_t*)(ws + OFF_EMB);
  float*    xz        = (float*)   (ws + OFF_XZ);
  float*    x_f32     = (float*)   (ws + OFF_X);
  float*    dbc       = (float*)   (ws + OFF_DBC);
  float*    dt_full   = (float*)   (ws + OFF_DT);
  ushort_t* y_bf      = (ushort_t*)(ws + OFF_Y);
  ushort_t* mo_bf     = (ushort_t*)(ws + OFF_MO);

  // 1) weight conversions to bf16
  cvt_bf16_kernel<<<(NXZ_ * DM_ / 4) / 256, 256, 0, stream>>>(in_proj_w, w_in_bf, NXZ_ * DM_ / 4);
  cvt_bf16_kernel<<<(DM_ * DI_ / 4) / 256, 256, 0, stream>>>(out_proj_w, w_out_bf, DM_ * DI_ / 4);
  cvt_bf16_kernel<<<(V_ * DM_ / 4) / 256, 256, 0, stream>>>(head_w, w_head_bf, V_ * DM_ / 4);
  // 2) embedding gather (f32 -> bf16)
  gather_kernel<<<(M_ * DM_ / 4) / 256, 256, 0, stream>>>(tokens, embed, emb_bf);
  // 3) in_proj: xz = emb @ in_proj_w^T  (f32 out)
  gemm_bt_kernel<0><<<dim3(NXZ_ / 128, M_ / 128), 256, 0, stream>>>(
      emb_bf, w_in_bf, xz, nullptr, nullptr, NXZ_, DM_);
  // 4) causal depthwise conv + SiLU -> x
  conv_silu_kernel<<<(M_ * DI_) / 256, 256, 0, stream>>>(xz, conv_w, conv_b, x_f32);
  // 5) x_proj -> dbc (f32)
  xproj_kernel<<<M_, 256, 0, stream>>>(x_f32, x_proj_w, dbc);
  // 6) dt_proj + softplus -> dt_full (f32)
  dtproj_kernel<<<M_, 256, 0, stream>>>(dbc, dt_proj_w, dt_proj_b, dt_full);
  // 7) selective scan + gating -> y (bf16)
  scan_kernel<<<B_ * (DI_ / 16), 256, 0, stream>>>(dt_full, x_f32, xz, dbc, A_log, Dvec, y_bf);
  // 8) out_proj: mo = y @ out_proj_w^T (bf16 out)
  gemm_bt_kernel<1><<<dim3(DM_ / 128, M_ / 128), 256, 0, stream>>>(
      y_bf, w_out_bf, nullptr, mo_bf, nullptr, DM_, DI_);
  // 9) head: out = mo @ head_w^T + head_b (f32 out)
  gemm_bt_kernel<2><<<dim3(V_ / 128, M_ / 128), 256, 0, stream>>>(
      mo_bf, w_head_bf, out, nullptr, head_b, V_, DM_);
}